// Round 1
// baseline (2337.178 us; speedup 1.0000x reference)
//
#include <hip/hip_runtime.h>
#include <math.h>

// Resnet50ContextualLoss: N=4, C=256, H=W=64 (P=4096), f32 in/out scalar.
// loss = mean_n -log( mean_q max_p softmax_row(alpha[p]*S[p,:])[q] + 1e-5 )
// S[n,p,q] = <xn[n,:,p], yn[n,:,q]>, alpha[p]=1/(h*(1-rowmax+eps)).

namespace {
constexpr int NB = 4;
constexpr int C  = 256;
constexpr int P  = 4096;
constexpr float EPSD = 1e-5f;
constexpr float EPSL = 1e-5f;
constexpr float HB   = 0.5f;

constexpr size_t OFF_MU    = 0;
constexpr size_t OFF_XN    = 256;
constexpr size_t OFF_YN    = OFF_XN + (size_t)NB * C * P;
constexpr size_t OFF_RMAX  = OFF_YN + (size_t)NB * C * P;
constexpr size_t OFF_ALPHA = OFF_RMAX + (size_t)NB * P;
constexpr size_t OFF_LROW  = OFF_ALPHA + (size_t)NB * P;
constexpr size_t OFF_CPART = OFF_LROW + (size_t)NB * P;
// total ~8.44M floats ~= 33.8 MB of ws
}  // namespace

// ---------- kernel 1: per-channel mean of y_hat over (n,h,w) ----------
__global__ void k_mu(const float* __restrict__ yh, float* __restrict__ ws) {
  const int c = blockIdx.x;
  const int t = threadIdx.x;
  float s = 0.f;
  for (int n = 0; n < NB; ++n) {
    const float* base = yh + ((size_t)(n * C + c)) * P;
    for (int p = t; p < P; p += 256) s += base[p];
  }
  __shared__ float red[256];
  red[t] = s;
  __syncthreads();
  for (int w = 128; w > 0; w >>= 1) {
    if (t < w) red[t] += red[t + w];
    __syncthreads();
  }
  if (t == 0) ws[OFF_MU + c] = red[0] * (1.0f / (NB * P));
}

// ---------- kernel 2: center + channel-L2-normalize both inputs ----------
// writes xn[n][c][p], yn[n][c][p]
__global__ void k_norm(const float* __restrict__ x, const float* __restrict__ y,
                       float* __restrict__ ws) {
  const int n  = blockIdx.x >> 6;
  const int p0 = (blockIdx.x & 63) << 6;
  const int t  = threadIdx.x;
  const int cl = t >> 6;   // 0..3
  const int pl = t & 63;   // 0..63

  __shared__ float mu_s[C];
  for (int i = t; i < C; i += 256) mu_s[i] = ws[OFF_MU + i];
  __syncthreads();

  float sx = 0.f, sy = 0.f;
  for (int cc = 0; cc < C; cc += 4) {
    const int c = cc + cl;
    const size_t idx = ((size_t)(n * C + c)) * P + p0 + pl;
    const float m = mu_s[c];
    const float xv = x[idx] - m;
    const float yv = y[idx] - m;
    sx += xv * xv;
    sy += yv * yv;
  }
  __shared__ float redx[4][64], redy[4][64];
  __shared__ float inx[64], iny[64];
  redx[cl][pl] = sx;
  redy[cl][pl] = sy;
  __syncthreads();
  if (t < 64) {
    const float tx = redx[0][t] + redx[1][t] + redx[2][t] + redx[3][t];
    const float ty = redy[0][t] + redy[1][t] + redy[2][t] + redy[3][t];
    inx[t] = 1.0f / sqrtf(tx);
    iny[t] = 1.0f / sqrtf(ty);
  }
  __syncthreads();
  const float invx = inx[pl], invy = iny[pl];
  float* xn = ws + OFF_XN;
  float* yn = ws + OFF_YN;
  for (int cc = 0; cc < C; cc += 4) {
    const int c = cc + cl;
    const size_t idx = ((size_t)(n * C + c)) * P + p0 + pl;
    const float m = mu_s[c];
    xn[idx] = (x[idx] - m) * invx;
    yn[idx] = (y[idx] - m) * invy;
  }
}

// ---------- kernels 3/4: row passes (PASS 0: rowmax->alpha, PASS 1: L) ----------
template <int PASS>
__global__ __launch_bounds__(256, 1) void k_rowpass(float* __restrict__ ws) {
  const int b  = blockIdx.x;
  const int n  = b >> 6;
  const int p0 = (b & 63) << 6;
  const int t  = threadIdx.x;
  const int tx = t & 15;   // q-group
  const int ty = t >> 4;   // p-group

  __shared__ __align__(16) float As[C][64];   // xn panel: [c][m], 64KB
  __shared__ __align__(16) float Bs[64][64];  // yn tile:  [k][j], 16KB
  __shared__ float red[64][17];

  const float* xn = ws + OFF_XN + (size_t)n * C * P;
  const float* yn = ws + OFF_YN + (size_t)n * C * P;

  // stage full A panel (rows p0..p0+63, all C)
  for (int i = t; i < C * 64; i += 256) {
    const int c = i >> 6, m = i & 63;
    As[c][m] = xn[(size_t)c * P + p0 + m];
  }
  __syncthreads();

  float runm[4], runs[4], av[4], rm[4];
#pragma unroll
  for (int i = 0; i < 4; ++i) { runm[i] = -1e30f; runs[i] = 0.f; }
  if (PASS == 1) {
#pragma unroll
    for (int i = 0; i < 4; ++i) {
      const int p = p0 + ty * 4 + i;
      av[i] = ws[OFF_ALPHA + (size_t)n * P + p];
      rm[i] = ws[OFF_RMAX + (size_t)n * P + p];
    }
  }

  for (int q0 = 0; q0 < P; q0 += 64) {
    float acc[4][4];
#pragma unroll
    for (int i = 0; i < 4; ++i)
#pragma unroll
      for (int j = 0; j < 4; ++j) acc[i][j] = 0.f;

    for (int c0 = 0; c0 < C; c0 += 64) {
      __syncthreads();  // protect Bs from previous use
      for (int i = t; i < 64 * 64; i += 256) {
        const int k = i >> 6, j = i & 63;
        Bs[k][j] = yn[(size_t)(c0 + k) * P + q0 + j];
      }
      __syncthreads();
#pragma unroll 4
      for (int k = 0; k < 64; ++k) {
        const float4 a = *reinterpret_cast<const float4*>(&As[c0 + k][ty << 2]);
        const float4 bq = *reinterpret_cast<const float4*>(&Bs[k][tx << 2]);
        const float ar[4] = {a.x, a.y, a.z, a.w};
        const float br[4] = {bq.x, bq.y, bq.z, bq.w};
#pragma unroll
        for (int i = 0; i < 4; ++i)
#pragma unroll
          for (int j = 0; j < 4; ++j) acc[i][j] = fmaf(ar[i], br[j], acc[i][j]);
      }
    }
    if (PASS == 0) {
#pragma unroll
      for (int i = 0; i < 4; ++i)
#pragma unroll
        for (int j = 0; j < 4; ++j) runm[i] = fmaxf(runm[i], acc[i][j]);
    } else {
#pragma unroll
      for (int i = 0; i < 4; ++i)
#pragma unroll
        for (int j = 0; j < 4; ++j)
          runs[i] += __expf(av[i] * (acc[i][j] - rm[i]));
    }
  }

  __syncthreads();
#pragma unroll
  for (int i = 0; i < 4; ++i)
    red[ty * 4 + i][tx] = (PASS == 0) ? runm[i] : runs[i];
  __syncthreads();
  if (t < 64) {
    float v = red[t][0];
    if (PASS == 0) {
      for (int j = 1; j < 16; ++j) v = fmaxf(v, red[t][j]);
      const float dmin  = 1.0f - v;
      const float alpha = 1.0f / (HB * (dmin + EPSD));
      ws[OFF_RMAX + (size_t)n * P + p0 + t]  = v;
      ws[OFF_ALPHA + (size_t)n * P + p0 + t] = alpha;
    } else {
      for (int j = 1; j < 16; ++j) v += red[t][j];
      const float a_ = ws[OFF_ALPHA + (size_t)n * P + p0 + t];
      const float m_ = ws[OFF_RMAX + (size_t)n * P + p0 + t];
      ws[OFF_LROW + (size_t)n * P + p0 + t] = a_ * m_ + logf(v);
    }
  }
}

// ---------- kernel 5: column pass -> per-(n,qtile) sum of exp(colmax) ----------
__global__ __launch_bounds__(256, 1) void k_colpass(float* __restrict__ ws) {
  const int b  = blockIdx.x;
  const int n  = b >> 6;
  const int q0 = (b & 63) << 6;
  const int t  = threadIdx.x;
  const int tx = t & 15;   // q-group
  const int ty = t >> 4;   // p-group

  __shared__ __align__(16) float Bp[C][64];   // yn panel: [c][j]
  __shared__ __align__(16) float At[64][64];  // xn tile:  [k][m]
  __shared__ float red[64][17];
  __shared__ float esum[64];

  const float* xn = ws + OFF_XN + (size_t)n * C * P;
  const float* yn = ws + OFF_YN + (size_t)n * C * P;

  for (int i = t; i < C * 64; i += 256) {
    const int c = i >> 6, j = i & 63;
    Bp[c][j] = yn[(size_t)c * P + q0 + j];
  }
  __syncthreads();

  float runc[4];
#pragma unroll
  for (int j = 0; j < 4; ++j) runc[j] = -1e30f;

  for (int p0 = 0; p0 < P; p0 += 64) {
    float acc[4][4];
#pragma unroll
    for (int i = 0; i < 4; ++i)
#pragma unroll
      for (int j = 0; j < 4; ++j) acc[i][j] = 0.f;
    float av[4], Lv[4];
#pragma unroll
    for (int i = 0; i < 4; ++i) {
      const int p = p0 + ty * 4 + i;
      av[i] = ws[OFF_ALPHA + (size_t)n * P + p];
      Lv[i] = ws[OFF_LROW + (size_t)n * P + p];
    }
    for (int c0 = 0; c0 < C; c0 += 64) {
      __syncthreads();
      for (int i = t; i < 64 * 64; i += 256) {
        const int k = i >> 6, m = i & 63;
        At[k][m] = xn[(size_t)(c0 + k) * P + p0 + m];
      }
      __syncthreads();
#pragma unroll 4
      for (int k = 0; k < 64; ++k) {
        const float4 a = *reinterpret_cast<const float4*>(&At[k][ty << 2]);
        const float4 bq = *reinterpret_cast<const float4*>(&Bp[c0 + k][tx << 2]);
        const float ar[4] = {a.x, a.y, a.z, a.w};
        const float br[4] = {bq.x, bq.y, bq.z, bq.w};
#pragma unroll
        for (int i = 0; i < 4; ++i)
#pragma unroll
          for (int j = 0; j < 4; ++j) acc[i][j] = fmaf(ar[i], br[j], acc[i][j]);
      }
    }
#pragma unroll
    for (int i = 0; i < 4; ++i)
#pragma unroll
      for (int j = 0; j < 4; ++j)
        runc[j] = fmaxf(runc[j], av[i] * acc[i][j] - Lv[i]);
  }

  __syncthreads();
#pragma unroll
  for (int j = 0; j < 4; ++j) red[tx * 4 + j][ty] = runc[j];
  __syncthreads();
  if (t < 64) {
    float v = red[t][0];
    for (int j = 1; j < 16; ++j) v = fmaxf(v, red[t][j]);
    esum[t] = __expf(v);
  }
  __syncthreads();
  if (t == 0) {
    float s = 0.f;
    for (int i = 0; i < 64; ++i) s += esum[i];
    ws[OFF_CPART + (size_t)n * 64 + (q0 >> 6)] = s;
  }
}

// ---------- kernel 6: final scalar ----------
__global__ void k_final(const float* __restrict__ ws, float* __restrict__ out) {
  const int t = threadIdx.x;
  __shared__ float per_n[NB];
  if (t < NB) {
    float s = 0.f;
    for (int i = 0; i < 64; ++i) s += ws[OFF_CPART + (size_t)t * 64 + i];
    const float cx = s * (1.0f / P);
    per_n[t] = -logf(cx + EPSL);
  }
  __syncthreads();
  if (t == 0)
    out[0] = 0.25f * (per_n[0] + per_n[1] + per_n[2] + per_n[3]);
}

extern "C" void kernel_launch(void* const* d_in, const int* in_sizes, int n_in,
                              void* d_out, int out_size, void* d_ws, size_t ws_size,
                              hipStream_t stream) {
  const float* x  = (const float*)d_in[0];  // y       (x in contextual_loss)
  const float* yh = (const float*)d_in[1];  // y_hat   ("y" in contextual_loss)
  float* ws  = (float*)d_ws;
  float* out = (float*)d_out;

  hipLaunchKernelGGL(k_mu, dim3(C), dim3(256), 0, stream, yh, ws);
  hipLaunchKernelGGL(k_norm, dim3(NB * 64), dim3(256), 0, stream, x, yh, ws);
  hipLaunchKernelGGL((k_rowpass<0>), dim3(NB * 64), dim3(256), 0, stream, ws);
  hipLaunchKernelGGL((k_rowpass<1>), dim3(NB * 64), dim3(256), 0, stream, ws);
  hipLaunchKernelGGL(k_colpass, dim3(NB * 64), dim3(256), 0, stream, ws);
  hipLaunchKernelGGL(k_final, dim3(1), dim3(64), 0, stream, ws, out);
}

// Round 2
// 730.410 us; speedup vs baseline: 3.1998x; 3.1998x over previous
//
#include <hip/hip_runtime.h>
#include <hip/hip_bf16.h>
#include <math.h>

// Resnet50ContextualLoss: N=4, C=256, H=W=64 (P=4096), f32 in / f32 scalar out.
// loss = mean_n -log( mean_q exp(colmax_q) + 1e-5 )
//   colmax_q = max_p [ alpha_p*S[p,q] - L_p ]
//   S[n,p,q] = <xn[n,:,p], yn[n,:,q]>  (bf16 MFMA, K=C=256)
//   alpha_p = 1/(h*(1-rowmax_p+eps)),  L_p = alpha_p*rowmax_p + log sum_q exp(alpha_p*(S-rowmax_p))

namespace {
constexpr int NB = 4;
constexpr int C  = 256;
constexpr int P  = 4096;
constexpr float EPSD = 1e-5f;
constexpr float EPSL = 1e-5f;
constexpr float HB   = 0.5f;

// ws layout in float units. xnT/ynT are bf16 [n][p][c] (ushort), so /2.
constexpr size_t OFF_MU    = 0;                                  // 256 f32
constexpr size_t OFF_XNT   = 256;                                // NB*P*C bf16
constexpr size_t OFF_YNT   = OFF_XNT + (size_t)NB * P * C / 2;
constexpr size_t OFF_RMAX  = OFF_YNT + (size_t)NB * P * C / 2;   // NB*P f32
constexpr size_t OFF_ALPHA = OFF_RMAX + (size_t)NB * P;
constexpr size_t OFF_LROW  = OFF_ALPHA + (size_t)NB * P;
constexpr size_t OFF_CPART = OFF_LROW + (size_t)NB * P;          // NB*64
// total ~4.25M floats ~= 17 MB
}  // namespace

typedef __attribute__((ext_vector_type(8))) __bf16 bf16x8;
typedef __attribute__((ext_vector_type(4))) float f32x4;

__device__ __forceinline__ bf16x8 ldfrag(const __bf16* p) {
  return *reinterpret_cast<const bf16x8*>(p);
}

// ---------- kernel 1: per-channel mean of y_hat over (n,h,w) ----------
__global__ void k_mu(const float* __restrict__ yh, float* __restrict__ ws) {
  const int c = blockIdx.x;
  const int t = threadIdx.x;
  float s = 0.f;
  for (int n = 0; n < NB; ++n) {
    const float* base = yh + ((size_t)(n * C + c)) * P;
    for (int p = t; p < P; p += 256) s += base[p];
  }
  __shared__ float red[256];
  red[t] = s;
  __syncthreads();
  for (int w = 128; w > 0; w >>= 1) {
    if (t < w) red[t] += red[t + w];
    __syncthreads();
  }
  if (t == 0) ws[OFF_MU + c] = red[0] * (1.0f / (NB * P));
}

// ---------- kernel 2: center + L2-normalize + transpose to bf16 [p][c] ----------
// grid: NB * 64 strips * 2 arrays; 256 threads.
__global__ __launch_bounds__(256) void k_norm(const float* __restrict__ x,
                                              const float* __restrict__ yh,
                                              float* __restrict__ ws) {
  const int b     = blockIdx.x;
  const int arr   = b & 1;
  const int strip = (b >> 1) & 63;
  const int n     = b >> 7;
  const int t     = threadIdx.x;
  const int w     = t >> 6;   // wave id 0..3 (one c-residue class each)
  const int l     = t & 63;   // p within strip

  __shared__ float mu_s[C];
  __shared__ float tile[64][257];  // centered values, [p_local][c]
  __shared__ float red[4][64];
  __shared__ float invs[64];

  mu_s[t] = ws[OFF_MU + t];
  __syncthreads();

  const float* src = arr ? yh : x;
  const size_t base = ((size_t)n * C) * P + (size_t)strip * 64 + l;
  float ssq = 0.f;
  for (int cc = 0; cc < C; cc += 4) {
    const int c = cc + w;
    const float v = src[base + (size_t)c * P] - mu_s[c];
    tile[l][c] = v;
    ssq += v * v;
  }
  red[w][l] = ssq;
  __syncthreads();
  if (t < 64) invs[t] = 1.0f / sqrtf(red[0][t] + red[1][t] + red[2][t] + red[3][t]);
  __syncthreads();

  uint* dst = reinterpret_cast<uint*>(ws + (arr ? OFF_YNT : OFF_XNT));
  const int c2 = t & 127;  // bf16-pair index (c = 2*c2, 2*c2+1)
  const size_t drow = ((size_t)n * P + (size_t)strip * 64) * (C / 2);
  for (int it = 0; it < 32; ++it) {
    const int pl = it * 2 + (t >> 7);
    const float s  = invs[pl];
    const float v0 = tile[pl][2 * c2] * s;
    const float v1 = tile[pl][2 * c2 + 1] * s;
    const unsigned short u0 = __builtin_bit_cast(unsigned short, __float2bfloat16(v0));
    const unsigned short u1 = __builtin_bit_cast(unsigned short, __float2bfloat16(v1));
    dst[drow + (size_t)pl * (C / 2) + c2] = ((uint)u1 << 16) | u0;
  }
}

// ---------- row passes: PASS0 rowmax->alpha, PASS1 rowsumexp->L ----------
// grid: NB*64 blocks (64-row strips), 512 threads = 8 waves.
// wave = row-tile (wave&3, 16 rows) x q-half (wave>>2, 2048 cols).
template <int PASS>
__global__ __launch_bounds__(512, 2) void k_row(float* __restrict__ ws) {
  const int t = threadIdx.x;
  const int wave = t >> 6, l = t & 63, l15 = l & 15, lh = l >> 4;
  const int n  = blockIdx.x >> 6;
  const int p0 = (blockIdx.x & 63) << 6;
  const int rt = wave & 3, half = wave >> 2;

  const __bf16* xn = reinterpret_cast<const __bf16*>(ws + OFF_XNT) + (size_t)n * P * C;
  const __bf16* yn = reinterpret_cast<const __bf16*>(ws + OFF_YNT) + (size_t)n * P * C;

  const int rowb = p0 + rt * 16;
  const __bf16* Ap = xn + (size_t)(rowb + l15) * C + lh * 8;
  bf16x8 af[8];
#pragma unroll
  for (int ks = 0; ks < 8; ++ks) af[ks] = ldfrag(Ap + ks * 32);

  float runv[4];
#pragma unroll
  for (int i = 0; i < 4; ++i) runv[i] = (PASS == 0) ? -3.0e38f : 0.f;
  float av[4], rm[4];
  if (PASS == 1) {
#pragma unroll
    for (int i = 0; i < 4; ++i) {
      const int p = rowb + lh * 4 + i;
      av[i] = ws[OFF_ALPHA + (size_t)n * P + p];
      rm[i] = ws[OFF_RMAX + (size_t)n * P + p];
    }
  }

  const int qbeg = half * 2048;
  for (int q = qbeg; q < qbeg + 2048; q += 64) {
    f32x4 acc[4];
#pragma unroll
    for (int jt = 0; jt < 4; ++jt) acc[jt] = (f32x4){0.f, 0.f, 0.f, 0.f};
    const __bf16* Bp = yn + (size_t)(q + l15) * C + lh * 8;
#pragma unroll
    for (int ks = 0; ks < 8; ++ks) {
#pragma unroll
      for (int jt = 0; jt < 4; ++jt)
        acc[jt] = __builtin_amdgcn_mfma_f32_16x16x32_bf16(
            af[ks], ldfrag(Bp + jt * (16 * C) + ks * 32), acc[jt], 0, 0, 0);
    }
    if (PASS == 0) {
#pragma unroll
      for (int jt = 0; jt < 4; ++jt)
#pragma unroll
        for (int i = 0; i < 4; ++i) runv[i] = fmaxf(runv[i], acc[jt][i]);
    } else {
#pragma unroll
      for (int jt = 0; jt < 4; ++jt)
#pragma unroll
        for (int i = 0; i < 4; ++i) runv[i] += __expf(av[i] * (acc[jt][i] - rm[i]));
    }
  }

  // reduce across the 16 col-lanes (l15); rows live on (lh, reg)
#pragma unroll
  for (int m = 1; m <= 8; m <<= 1) {
#pragma unroll
    for (int i = 0; i < 4; ++i) {
      const float o = __shfl_xor(runv[i], m, 64);
      runv[i] = (PASS == 0) ? fmaxf(runv[i], o) : (runv[i] + o);
    }
  }
  __shared__ float red[8][16];
  if (l15 == 0) {
#pragma unroll
    for (int i = 0; i < 4; ++i) red[wave][lh * 4 + i] = runv[i];
  }
  __syncthreads();
  if (t < 64) {
    const int rti = t >> 4, rl = t & 15;
    const float v0 = red[rti][rl], v1 = red[rti + 4][rl];
    const int p = p0 + t;
    if (PASS == 0) {
      const float mx = fmaxf(v0, v1);
      ws[OFF_RMAX + (size_t)n * P + p]  = mx;
      ws[OFF_ALPHA + (size_t)n * P + p] = 1.0f / (HB * (1.0f - mx + EPSD));
    } else {
      const float s  = v0 + v1;
      const float a  = ws[OFF_ALPHA + (size_t)n * P + p];
      const float mx = ws[OFF_RMAX + (size_t)n * P + p];
      ws[OFF_LROW + (size_t)n * P + p] = a * mx + logf(s);
    }
  }
}

// ---------- col pass: colmax of alpha*S - L, then sum exp per 64-col strip ----------
// grid: NB*64 blocks (64-col strips), 512 threads = 8 waves.
// wave = col-tile (wave&3: 16 q's as MFMA rows) x p-half (wave>>2).
__global__ __launch_bounds__(512, 2) void k_col(float* __restrict__ ws) {
  const int t = threadIdx.x;
  const int wave = t >> 6, l = t & 63, l15 = l & 15, lh = l >> 4;
  const int n  = blockIdx.x >> 6;
  const int q0 = (blockIdx.x & 63) << 6;
  const int ct = wave & 3, half = wave >> 2;

  const __bf16* xn = reinterpret_cast<const __bf16*>(ws + OFF_XNT) + (size_t)n * P * C;
  const __bf16* yn = reinterpret_cast<const __bf16*>(ws + OFF_YNT) + (size_t)n * P * C;
  const float* alp = ws + OFF_ALPHA + (size_t)n * P;
  const float* lrw = ws + OFF_LROW + (size_t)n * P;

  const __bf16* Ap = yn + (size_t)(q0 + ct * 16 + l15) * C + lh * 8;
  bf16x8 af[8];
#pragma unroll
  for (int ks = 0; ks < 8; ++ks) af[ks] = ldfrag(Ap + ks * 32);

  float runc[4];
#pragma unroll
  for (int i = 0; i < 4; ++i) runc[i] = -3.0e38f;

  const int pbeg = half * 2048;
  for (int p = pbeg; p < pbeg + 2048; p += 64) {
    f32x4 acc[4];
#pragma unroll
    for (int jt = 0; jt < 4; ++jt) acc[jt] = (f32x4){0.f, 0.f, 0.f, 0.f};
    const __bf16* Bp = xn + (size_t)(p + l15) * C + lh * 8;
#pragma unroll
    for (int ks = 0; ks < 8; ++ks) {
#pragma unroll
      for (int jt = 0; jt < 4; ++jt)
        acc[jt] = __builtin_amdgcn_mfma_f32_16x16x32_bf16(
            af[ks], ldfrag(Bp + jt * (16 * C) + ks * 32), acc[jt], 0, 0, 0);
    }
#pragma unroll
    for (int jt = 0; jt < 4; ++jt) {
      const int pc = p + jt * 16 + l15;  // this lane's p (MFMA col)
      const float a = alp[pc], L = lrw[pc];
#pragma unroll
      for (int i = 0; i < 4; ++i) runc[i] = fmaxf(runc[i], a * acc[jt][i] - L);
    }
  }

#pragma unroll
  for (int m = 1; m <= 8; m <<= 1) {
#pragma unroll
    for (int i = 0; i < 4; ++i) runc[i] = fmaxf(runc[i], __shfl_xor(runc[i], m, 64));
  }
  __shared__ float red[8][16];
  if (l15 == 0) {
#pragma unroll
    for (int i = 0; i < 4; ++i) red[wave][lh * 4 + i] = runc[i];
  }
  __syncthreads();
  if (t < 64) {
    const int cti = t >> 4, rl = t & 15;
    float e = __expf(fmaxf(red[cti][rl], red[cti + 4][rl]));
#pragma unroll
    for (int m = 1; m <= 32; m <<= 1) e += __shfl_xor(e, m, 64);
    if (t == 0) ws[OFF_CPART + (size_t)n * 64 + (q0 >> 6)] = e;
  }
}

// ---------- final scalar ----------
__global__ void k_final(const float* __restrict__ ws, float* __restrict__ out) {
  const int t = threadIdx.x;
  __shared__ float per_n[NB];
  if (t < NB) {
    float s = 0.f;
    for (int i = 0; i < 64; ++i) s += ws[OFF_CPART + (size_t)t * 64 + i];
    per_n[t] = -logf(s * (1.0f / P) + EPSL);
  }
  __syncthreads();
  if (t == 0)
    out[0] = 0.25f * (per_n[0] + per_n[1] + per_n[2] + per_n[3]);
}

extern "C" void kernel_launch(void* const* d_in, const int* in_sizes, int n_in,
                              void* d_out, int out_size, void* d_ws, size_t ws_size,
                              hipStream_t stream) {
  const float* x  = (const float*)d_in[0];  // y      -> x in contextual_loss
  const float* yh = (const float*)d_in[1];  // y_hat  -> y in contextual_loss
  float* ws  = (float*)d_ws;
  float* out = (float*)d_out;

  k_mu<<<dim3(C), dim3(256), 0, stream>>>(yh, ws);
  k_norm<<<dim3(NB * 64 * 2), dim3(256), 0, stream>>>(x, yh, ws);
  k_row<0><<<dim3(NB * 64), dim3(512), 0, stream>>>(ws);
  k_row<1><<<dim3(NB * 64), dim3(512), 0, stream>>>(ws);
  k_col<<<dim3(NB * 64), dim3(512), 0, stream>>>(ws);
  k_final<<<dim3(1), dim3(64), 0, stream>>>(ws, out);
}

// Round 3
// 189.827 us; speedup vs baseline: 12.3122x; 3.8478x over previous
//
#include <hip/hip_runtime.h>
#include <hip/hip_bf16.h>
#include <math.h>

// Resnet50ContextualLoss: N=4, C=256, H=W=64 (P=4096), f32 in / f32 scalar out.
// loss = mean_n -log( mean_q exp(colmax_q) + 1e-5 )
//   colmax_q = max_p [ alpha_p*S[p,q] - L_p ]
//   S[n,p,q] = <xn[n,:,p], yn[n,:,q]>  (bf16 MFMA 32x32x16, K=C=256)
//   alpha_p = 1/(h*(1-rowmax_p+eps)),  L_p = alpha_p*rowmax_p + log sum_q exp(alpha_p*(S-rowmax_p))

namespace {
constexpr int NB = 4;
constexpr int C  = 256;
constexpr int P  = 4096;
constexpr float EPSD = 1e-5f;
constexpr float EPSL = 1e-5f;
constexpr float HB   = 0.5f;

// ws layout in float units. xnT/ynT are bf16 [n][p][c], so /2.
constexpr size_t OFF_MU    = 0;                                  // 256 f32
constexpr size_t OFF_XNT   = 256;                                // NB*P*C bf16
constexpr size_t OFF_YNT   = OFF_XNT + (size_t)NB * P * C / 2;
constexpr size_t OFF_RMAX  = OFF_YNT + (size_t)NB * P * C / 2;   // NB*P f32
constexpr size_t OFF_ALPHA = OFF_RMAX + (size_t)NB * P;
constexpr size_t OFF_LROW  = OFF_ALPHA + (size_t)NB * P;
constexpr size_t OFF_CPART = OFF_LROW + (size_t)NB * P;          // NB*64
}  // namespace

typedef __attribute__((ext_vector_type(8))) __bf16 bf16x8;
typedef __attribute__((ext_vector_type(16))) float f32x16;
typedef unsigned short u16;

__device__ __forceinline__ bf16x8 ldfrag(const u16* p) {
  return *reinterpret_cast<const bf16x8*>(p);
}
__device__ __forceinline__ void gload_lds16(const u16* g, u16* l) {
  __builtin_amdgcn_global_load_lds(
      (const __attribute__((address_space(1))) void*)g,
      (__attribute__((address_space(3))) void*)l, 16, 0, 0);
}
__device__ __forceinline__ f32x16 zero16() {
  f32x16 z;
#pragma unroll
  for (int i = 0; i < 16; ++i) z[i] = 0.f;
  return z;
}

// Stage a [128 x 256] bf16 tile (rows row0..row0+127 of src[p][c]) into LDS.
// LDS dest is LINEAR (required by global_load_lds); the global SOURCE is
// pre-swizzled (16B-granule ^ (row&15)) so reads at (granule ^ (row&15))
// retrieve true data with conflict-free bank spread (rule #21 pattern).
__device__ __forceinline__ void stage_tile(const u16* __restrict__ src, int row0,
                                           u16* lds, int t) {
#pragma unroll
  for (int i = 0; i < 8; ++i) {
    const int g  = i * 512 + t;          // granule 0..4095
    const int r  = g >> 5;               // tile row 0..127
    const int gs = (g & 31) ^ (r & 15);  // pre-swizzled source granule
    gload_lds16(src + (size_t)(row0 + r) * 256 + gs * 8, lds + (size_t)g * 8);
  }
}

// ---------- kernel 1: per-channel mean of y_hat over (n,h,w) ----------
__global__ void k_mu(const float* __restrict__ yh, float* __restrict__ ws) {
  const int c = blockIdx.x;
  const int t = threadIdx.x;
  float s = 0.f;
  for (int n = 0; n < NB; ++n) {
    const float* base = yh + ((size_t)(n * C + c)) * P;
    for (int p = t; p < P; p += 256) s += base[p];
  }
  __shared__ float red[256];
  red[t] = s;
  __syncthreads();
  for (int w = 128; w > 0; w >>= 1) {
    if (t < w) red[t] += red[t + w];
    __syncthreads();
  }
  if (t == 0) ws[OFF_MU + c] = red[0] * (1.0f / (NB * P));
}

// ---------- kernel 2: center + L2-normalize + transpose to bf16 [p][c] ----------
__global__ __launch_bounds__(256) void k_norm(const float* __restrict__ x,
                                              const float* __restrict__ yh,
                                              float* __restrict__ ws) {
  const int b     = blockIdx.x;
  const int arr   = b & 1;
  const int strip = (b >> 1) & 63;
  const int n     = b >> 7;
  const int t     = threadIdx.x;
  const int w     = t >> 6;
  const int l     = t & 63;

  __shared__ float mu_s[C];
  __shared__ float tile[64][257];
  __shared__ float red[4][64];
  __shared__ float invs[64];

  mu_s[t] = ws[OFF_MU + t];
  __syncthreads();

  const float* src = arr ? yh : x;
  const size_t base = ((size_t)n * C) * P + (size_t)strip * 64 + l;
  float ssq = 0.f;
  for (int cc = 0; cc < C; cc += 4) {
    const int c = cc + w;
    const float v = src[base + (size_t)c * P] - mu_s[c];
    tile[l][c] = v;
    ssq += v * v;
  }
  red[w][l] = ssq;
  __syncthreads();
  if (t < 64) invs[t] = 1.0f / sqrtf(red[0][t] + red[1][t] + red[2][t] + red[3][t]);
  __syncthreads();

  uint* dst = reinterpret_cast<uint*>(ws + (arr ? OFF_YNT : OFF_XNT));
  const int c2 = t & 127;
  const size_t drow = ((size_t)n * P + (size_t)strip * 64) * (C / 2);
  for (int it = 0; it < 32; ++it) {
    const int pl = it * 2 + (t >> 7);
    const float s  = invs[pl];
    const float v0 = tile[pl][2 * c2] * s;
    const float v1 = tile[pl][2 * c2 + 1] * s;
    const unsigned short u0 = __builtin_bit_cast(unsigned short, __float2bfloat16(v0));
    const unsigned short u1 = __builtin_bit_cast(unsigned short, __float2bfloat16(v1));
    dst[drow + (size_t)pl * (C / 2) + c2] = ((uint)u1 << 16) | u0;
  }
}

// ---------- row passes (PASS0: rowmax->alpha, PASS1: rowsumexp->L) ----------
// block = 64-row strip, 512 thr = 8 waves = 2 row-tiles(rt,32 rows) x 4 col-sub(ct).
// A (xn rows) resident in regs; B (yn) staged 128x256 per step, double-buffered.
template <int PASS>
__global__ __launch_bounds__(512, 2) void k_row(float* __restrict__ ws) {
  const int t = threadIdx.x;
  const int wave = t >> 6, l = t & 63, l31 = l & 31, lh = l >> 5;
  const int rt = wave >> 2, ct = wave & 3;
  const int n  = blockIdx.x >> 6;
  const int p0 = (blockIdx.x & 63) << 6;

  const u16* xn = reinterpret_cast<const u16*>(ws + OFF_XNT) + (size_t)n * P * C;
  const u16* yn = reinterpret_cast<const u16*>(ws + OFF_YNT) + (size_t)n * P * C;

  __shared__ __align__(16) u16 Bl[2][128 * 256];
  __shared__ float red[8][32];

  // A fragments: rows p0 + rt*32 + l31, k-granules ks*2+lh
  const u16* Ap = xn + (size_t)(p0 + rt * 32 + l31) * 256;
  bf16x8 af[16];
#pragma unroll
  for (int ks = 0; ks < 16; ++ks) af[ks] = ldfrag(Ap + (ks * 2 + lh) * 8);

  float av[16], rm[16];
  if (PASS == 1) {
#pragma unroll
    for (int r = 0; r < 16; ++r) {
      const int row = (r & 3) + 8 * (r >> 2) + 4 * lh;
      const int p = p0 + rt * 32 + row;
      av[r] = ws[OFF_ALPHA + (size_t)n * P + p];
      rm[r] = ws[OFF_RMAX + (size_t)n * P + p];
    }
  }

  float run[16];
#pragma unroll
  for (int r = 0; r < 16; ++r) run[r] = (PASS == 0) ? -3.0e38f : 0.f;

  stage_tile(yn, 0, Bl[0], t);
  __syncthreads();

  const int q_local = ct * 32 + l31;
  const int qsw = q_local & 15;
  const u16* Brow0 = &Bl[0][(size_t)q_local * 256];
  const u16* Brow1 = &Bl[1][(size_t)q_local * 256];

  for (int step = 0; step < 32; ++step) {
    const int cur = step & 1;
    if (step + 1 < 32) stage_tile(yn, (step + 1) * 128, Bl[cur ^ 1], t);
    const u16* Brow = cur ? Brow1 : Brow0;

    f32x16 acc0 = zero16(), acc1 = zero16();
#pragma unroll
    for (int ks = 0; ks < 16; ks += 2) {
      acc0 = __builtin_amdgcn_mfma_f32_32x32x16_bf16(
          af[ks], ldfrag(Brow + (((ks * 2 + lh)) ^ qsw) * 8), acc0, 0, 0, 0);
      acc1 = __builtin_amdgcn_mfma_f32_32x32x16_bf16(
          af[ks + 1], ldfrag(Brow + (((ks * 2 + 2 + lh)) ^ qsw) * 8), acc1, 0, 0, 0);
    }
    const f32x16 acc = acc0 + acc1;

    if (PASS == 0) {
#pragma unroll
      for (int r = 0; r < 16; ++r) run[r] = fmaxf(run[r], acc[r]);
    } else {
#pragma unroll
      for (int r = 0; r < 16; ++r) run[r] += __expf(av[r] * (acc[r] - rm[r]));
    }
    __syncthreads();
  }

  // reduce over the 32 col-lanes; rows live on (reg, lh)
#pragma unroll
  for (int m = 1; m <= 16; m <<= 1) {
#pragma unroll
    for (int r = 0; r < 16; ++r) {
      const float o = __shfl_xor(run[r], m, 64);
      run[r] = (PASS == 0) ? fmaxf(run[r], o) : (run[r] + o);
    }
  }
  if (l31 == 0) {
#pragma unroll
    for (int r = 0; r < 16; ++r)
      red[wave][(r & 3) + 8 * (r >> 2) + 4 * lh] = run[r];
  }
  __syncthreads();
  if (t < 64) {
    const int rt2 = t >> 5, row = t & 31;
    const int p = p0 + rt2 * 32 + row;
    if (PASS == 0) {
      float v = red[rt2 * 4][row];
#pragma unroll
      for (int j = 1; j < 4; ++j) v = fmaxf(v, red[rt2 * 4 + j][row]);
      ws[OFF_RMAX + (size_t)n * P + p]  = v;
      ws[OFF_ALPHA + (size_t)n * P + p] = 1.0f / (HB * (1.0f - v + EPSD));
    } else {
      float s = red[rt2 * 4][row];
#pragma unroll
      for (int j = 1; j < 4; ++j) s += red[rt2 * 4 + j][row];
      const float a_ = ws[OFF_ALPHA + (size_t)n * P + p];
      const float m_ = ws[OFF_RMAX + (size_t)n * P + p];
      ws[OFF_LROW + (size_t)n * P + p] = a_ * m_ + logf(s);
    }
  }
}

// ---------- col pass: colmax_q = max_p (alpha*S - L); exp+sum per strip ----------
// block = 64-q strip; A (yn rows) resident; B (xn) staged per 128-p step.
__global__ __launch_bounds__(512, 2) void k_col(float* __restrict__ ws) {
  const int t = threadIdx.x;
  const int wave = t >> 6, l = t & 63, l31 = l & 31, lh = l >> 5;
  const int rt = wave >> 2, ct = wave & 3;
  const int n  = blockIdx.x >> 6;
  const int q0 = (blockIdx.x & 63) << 6;

  const u16* xn = reinterpret_cast<const u16*>(ws + OFF_XNT) + (size_t)n * P * C;
  const u16* yn = reinterpret_cast<const u16*>(ws + OFF_YNT) + (size_t)n * P * C;
  const float* alp = ws + OFF_ALPHA + (size_t)n * P;
  const float* lrw = ws + OFF_LROW + (size_t)n * P;

  __shared__ __align__(16) u16 Bl[2][128 * 256];
  __shared__ float red[8][32];

  const u16* Ap = yn + (size_t)(q0 + rt * 32 + l31) * 256;
  bf16x8 af[16];
#pragma unroll
  for (int ks = 0; ks < 16; ++ks) af[ks] = ldfrag(Ap + (ks * 2 + lh) * 8);

  float run[16];
#pragma unroll
  for (int r = 0; r < 16; ++r) run[r] = -3.0e38f;

  stage_tile(xn, 0, Bl[0], t);
  __syncthreads();

  const int p_local = ct * 32 + l31;
  const int psw = p_local & 15;
  const u16* Brow0 = &Bl[0][(size_t)p_local * 256];
  const u16* Brow1 = &Bl[1][(size_t)p_local * 256];

  for (int step = 0; step < 32; ++step) {
    const int cur = step & 1;
    if (step + 1 < 32) stage_tile(xn, (step + 1) * 128, Bl[cur ^ 1], t);
    const u16* Brow = cur ? Brow1 : Brow0;

    const int pcol = step * 128 + p_local;
    const float a_ = alp[pcol];
    const float L_ = lrw[pcol];

    f32x16 acc0 = zero16(), acc1 = zero16();
#pragma unroll
    for (int ks = 0; ks < 16; ks += 2) {
      acc0 = __builtin_amdgcn_mfma_f32_32x32x16_bf16(
          af[ks], ldfrag(Brow + (((ks * 2 + lh)) ^ psw) * 8), acc0, 0, 0, 0);
      acc1 = __builtin_amdgcn_mfma_f32_32x32x16_bf16(
          af[ks + 1], ldfrag(Brow + (((ks * 2 + 2 + lh)) ^ psw) * 8), acc1, 0, 0, 0);
    }
    const f32x16 acc = acc0 + acc1;
#pragma unroll
    for (int r = 0; r < 16; ++r) run[r] = fmaxf(run[r], fmaf(a_, acc[r], -L_));
    __syncthreads();
  }

  // max over the 32 p-lanes; q rows live on (reg, lh)
#pragma unroll
  for (int m = 1; m <= 16; m <<= 1) {
#pragma unroll
    for (int r = 0; r < 16; ++r) run[r] = fmaxf(run[r], __shfl_xor(run[r], m, 64));
  }
  if (l31 == 0) {
#pragma unroll
    for (int r = 0; r < 16; ++r)
      red[wave][(r & 3) + 8 * (r >> 2) + 4 * lh] = run[r];
  }
  __syncthreads();
  if (t < 64) {
    const int rt2 = t >> 5, row = t & 31;
    float v = red[rt2 * 4][row];
#pragma unroll
    for (int j = 1; j < 4; ++j) v = fmaxf(v, red[rt2 * 4 + j][row]);
    float e = __expf(v);
#pragma unroll
    for (int m = 1; m <= 32; m <<= 1) e += __shfl_xor(e, m, 64);
    if (t == 0) ws[OFF_CPART + (size_t)n * 64 + (q0 >> 6)] = e;
  }
}

// ---------- final scalar ----------
__global__ void k_final(const float* __restrict__ ws, float* __restrict__ out) {
  const int t = threadIdx.x;
  __shared__ float per_n[NB];
  if (t < NB) {
    float s = 0.f;
    for (int i = 0; i < 64; ++i) s += ws[OFF_CPART + (size_t)t * 64 + i];
    per_n[t] = -logf(s * (1.0f / P) + EPSL);
  }
  __syncthreads();
  if (t == 0)
    out[0] = 0.25f * (per_n[0] + per_n[1] + per_n[2] + per_n[3]);
}

extern "C" void kernel_launch(void* const* d_in, const int* in_sizes, int n_in,
                              void* d_out, int out_size, void* d_ws, size_t ws_size,
                              hipStream_t stream) {
  const float* x  = (const float*)d_in[0];  // y      -> x in contextual_loss
  const float* yh = (const float*)d_in[1];  // y_hat  -> y in contextual_loss
  float* ws  = (float*)d_ws;
  float* out = (float*)d_out;

  k_mu<<<dim3(C), dim3(256), 0, stream>>>(yh, ws);
  k_norm<<<dim3(NB * 64 * 2), dim3(256), 0, stream>>>(x, yh, ws);
  k_row<0><<<dim3(NB * 64), dim3(512), 0, stream>>>(ws);
  k_row<1><<<dim3(NB * 64), dim3(512), 0, stream>>>(ws);
  k_col<<<dim3(NB * 64), dim3(512), 0, stream>>>(ws);
  k_final<<<dim3(1), dim3(64), 0, stream>>>(ws, out);
}

// Round 4
// 173.463 us; speedup vs baseline: 13.4736x; 1.0943x over previous
//
#include <hip/hip_runtime.h>
#include <hip/hip_bf16.h>
#include <math.h>

// Resnet50ContextualLoss: N=4, C=256, H=W=64 (P=4096), f32 in / f32 scalar out.
// loss = mean_n -log( mean_q exp(colmax_q) + 1e-5 )
//   colmax_q = max_p [ alpha_p*S[p,q] - L_p ]
//   S[n,p,q] = <xn[n,:,p], yn[n,:,q]>  (bf16 MFMA 32x32x16, K=C=256)
//   alpha_p = 1/(h*(1-rowmax_p+eps)),  L_p = alpha_p*rowmax_p + log sum_q exp(alpha_p*(S-rowmax_p))
// GEMM passes: 128-row strips x 2 halves, XCD-pinned (bid%8 = (n,half)).

namespace {
constexpr int NB = 4;
constexpr int C  = 256;
constexpr int P  = 4096;
constexpr float EPSD = 1e-5f;
constexpr float EPSL = 1e-5f;
constexpr float HB   = 0.5f;

// ws layout in float units. xnT/ynT are bf16 [n][p][c], so /2.
constexpr size_t OFF_MU    = 0;                                   // 256 f32
constexpr size_t OFF_XNT   = 256;                                 // NB*P*C bf16
constexpr size_t OFF_YNT   = OFF_XNT + (size_t)NB * P * C / 2;
constexpr size_t OFF_RMAXH = OFF_YNT + (size_t)NB * P * C / 2;    // [NB*2][P]
constexpr size_t OFF_SUMH  = OFF_RMAXH + (size_t)NB * 2 * P;      // [NB*2][P]
constexpr size_t OFF_CMAXH = OFF_SUMH + (size_t)NB * 2 * P;       // [NB*2][P]
constexpr size_t OFF_RMAX  = OFF_CMAXH + (size_t)NB * 2 * P;      // [NB][P]
constexpr size_t OFF_ALPHA = OFF_RMAX + (size_t)NB * P;
constexpr size_t OFF_LROW  = OFF_ALPHA + (size_t)NB * P;
}  // namespace

typedef __attribute__((ext_vector_type(8))) __bf16 bf16x8;
typedef __attribute__((ext_vector_type(16))) float f32x16;
typedef unsigned short u16;

__device__ __forceinline__ bf16x8 ldfrag(const u16* p) {
  return *reinterpret_cast<const bf16x8*>(p);
}
__device__ __forceinline__ void gload_lds16(const u16* g, u16* l) {
  __builtin_amdgcn_global_load_lds(
      (const __attribute__((address_space(1))) void*)g,
      (__attribute__((address_space(3))) void*)l, 16, 0, 0);
}
__device__ __forceinline__ f32x16 zero16() {
  f32x16 z;
#pragma unroll
  for (int i = 0; i < 16; ++i) z[i] = 0.f;
  return z;
}

// Stage a [128 x 256] bf16 tile (rows row0..row0+127 of src[p][c]) into LDS.
// LDS dest LINEAR (global_load_lds requirement); global SOURCE pre-swizzled
// (16B-granule ^ (row&15)); reads apply the same XOR (rule #21).
__device__ __forceinline__ void stage_tile(const u16* __restrict__ src, int row0,
                                           u16* lds, int t) {
#pragma unroll
  for (int i = 0; i < 8; ++i) {
    const int g  = i * 512 + t;          // granule 0..4095
    const int r  = g >> 5;               // tile row 0..127
    const int gs = (g & 31) ^ (r & 15);  // pre-swizzled source granule
    gload_lds16(src + (size_t)(row0 + r) * 256 + gs * 8, lds + (size_t)g * 8);
  }
}

// ---------- kernel 1: per-channel mean of y_hat over (n,h,w) ----------
__global__ void k_mu(const float* __restrict__ yh, float* __restrict__ ws) {
  const int c = blockIdx.x;
  const int t = threadIdx.x;
  float s = 0.f;
  for (int n = 0; n < NB; ++n) {
    const float* base = yh + ((size_t)(n * C + c)) * P;
    for (int p = t; p < P; p += 256) s += base[p];
  }
  __shared__ float red[256];
  red[t] = s;
  __syncthreads();
  for (int w = 128; w > 0; w >>= 1) {
    if (t < w) red[t] += red[t + w];
    __syncthreads();
  }
  if (t == 0) ws[OFF_MU + c] = red[0] * (1.0f / (NB * P));
}

// ---------- kernel 2: center + L2-normalize + transpose to bf16 [p][c] ----------
__global__ __launch_bounds__(256) void k_norm(const float* __restrict__ x,
                                              const float* __restrict__ yh,
                                              float* __restrict__ ws) {
  const int b     = blockIdx.x;
  const int arr   = b & 1;
  const int strip = (b >> 1) & 63;
  const int n     = b >> 7;
  const int t     = threadIdx.x;
  const int w     = t >> 6;
  const int l     = t & 63;

  __shared__ float mu_s[C];
  __shared__ float tile[64][257];
  __shared__ float red[4][64];
  __shared__ float invs[64];

  mu_s[t] = ws[OFF_MU + t];
  __syncthreads();

  const float* src = arr ? yh : x;
  const size_t base = ((size_t)n * C) * P + (size_t)strip * 64 + l;
  float ssq = 0.f;
  for (int cc = 0; cc < C; cc += 4) {
    const int c = cc + w;
    const float v = src[base + (size_t)c * P] - mu_s[c];
    tile[l][c] = v;
    ssq += v * v;
  }
  red[w][l] = ssq;
  __syncthreads();
  if (t < 64) invs[t] = 1.0f / sqrtf(red[0][t] + red[1][t] + red[2][t] + red[3][t]);
  __syncthreads();

  uint* dst = reinterpret_cast<uint*>(ws + (arr ? OFF_YNT : OFF_XNT));
  const int c2 = t & 127;
  const size_t drow = ((size_t)n * P + (size_t)strip * 64) * (C / 2);
  for (int it = 0; it < 32; ++it) {
    const int pl = it * 2 + (t >> 7);
    const float s  = invs[pl];
    const float v0 = tile[pl][2 * c2] * s;
    const float v1 = tile[pl][2 * c2 + 1] * s;
    const unsigned short u0 = __builtin_bit_cast(unsigned short, __float2bfloat16(v0));
    const unsigned short u1 = __builtin_bit_cast(unsigned short, __float2bfloat16(v1));
    dst[drow + (size_t)pl * (C / 2) + c2] = ((uint)u1 << 16) | u0;
  }
}

// ---------- row passes (PASS0: partial rowmax, PASS1: partial rowsumexp) ----------
// bid = strip*8 + n*2 + qhalf  (XCD-pinned). Block: 128 rows x 2048 q.
// 8 waves = 4 row-tiles(rt,32 rows) x 2 col-groups(ct,64 q = 2 sub-tiles).
template <int PASS>
__global__ __launch_bounds__(512, 2) void k_row(float* __restrict__ ws) {
  const int t = threadIdx.x;
  const int wave = t >> 6, l = t & 63, l31 = l & 31, lh = l >> 5, l15 = l31 & 15;
  const int rt = wave >> 1, ct = wave & 1;
  const int bid = blockIdx.x;
  const int qhalf = bid & 1, n = (bid >> 1) & 3, strip = bid >> 3;
  const int p0 = strip * 128;
  const int qbase = qhalf * 2048;

  const u16* xn = reinterpret_cast<const u16*>(ws + OFF_XNT) + (size_t)n * P * C;
  const u16* yn = reinterpret_cast<const u16*>(ws + OFF_YNT) + (size_t)n * P * C;

  __shared__ __align__(16) u16 Bl[2][128 * 256];
  __shared__ float red[8][32];

  // A fragments: rows p0 + rt*32 + l31, all K=256
  const u16* Ap = xn + (size_t)(p0 + rt * 32 + l31) * 256;
  bf16x8 af[16];
#pragma unroll
  for (int ks = 0; ks < 16; ++ks) af[ks] = ldfrag(Ap + (ks * 2 + lh) * 8);

  float av[16], arm[16];
  if (PASS == 1) {
#pragma unroll
    for (int r = 0; r < 16; ++r) {
      const int row = (r & 3) + 8 * (r >> 2) + 4 * lh;
      const int p = p0 + rt * 32 + row;
      const float a_ = ws[OFF_ALPHA + (size_t)n * P + p];
      av[r]  = a_;
      arm[r] = a_ * ws[OFF_RMAX + (size_t)n * P + p];
    }
  }

  float run[16];
#pragma unroll
  for (int r = 0; r < 16; ++r) run[r] = (PASS == 0) ? -3.0e38f : 0.f;

  stage_tile(yn, qbase, Bl[0], t);
  __syncthreads();

  const int r0 = ct * 64 + l31;  // LDS row of sub-tile 0 (sub1 = +32)

  for (int step = 0; step < 16; ++step) {
    const int cur = step & 1;
    if (step + 1 < 16) stage_tile(yn, qbase + (step + 1) * 128, Bl[cur ^ 1], t);
    const u16* Brow = &Bl[cur][(size_t)r0 * 256];

    f32x16 a00 = zero16(), a01 = zero16(), a10 = zero16(), a11 = zero16();
#pragma unroll
    for (int ks = 0; ks < 16; ks += 2) {
      const int g0 = ((ks * 2 + lh) ^ l15) * 8;
      const int g1 = ((ks * 2 + 2 + lh) ^ l15) * 8;
      a00 = __builtin_amdgcn_mfma_f32_32x32x16_bf16(af[ks], ldfrag(Brow + g0), a00, 0, 0, 0);
      a10 = __builtin_amdgcn_mfma_f32_32x32x16_bf16(af[ks], ldfrag(Brow + 32 * 256 + g0), a10, 0, 0, 0);
      a01 = __builtin_amdgcn_mfma_f32_32x32x16_bf16(af[ks + 1], ldfrag(Brow + g1), a01, 0, 0, 0);
      a11 = __builtin_amdgcn_mfma_f32_32x32x16_bf16(af[ks + 1], ldfrag(Brow + 32 * 256 + g1), a11, 0, 0, 0);
    }
    const f32x16 s0 = a00 + a01;
    const f32x16 s1 = a10 + a11;

    if (PASS == 0) {
#pragma unroll
      for (int r = 0; r < 16; ++r) run[r] = fmaxf(run[r], fmaxf(s0[r], s1[r]));
    } else {
#pragma unroll
      for (int r = 0; r < 16; ++r)
        run[r] += __expf(fmaf(av[r], s0[r], -arm[r])) + __expf(fmaf(av[r], s1[r], -arm[r]));
    }
    __syncthreads();
  }

  // reduce across the 32 q-lanes; rows live on (reg, lh)
#pragma unroll
  for (int m = 1; m <= 16; m <<= 1) {
#pragma unroll
    for (int r = 0; r < 16; ++r) {
      const float o = __shfl_xor(run[r], m, 64);
      run[r] = (PASS == 0) ? fmaxf(run[r], o) : (run[r] + o);
    }
  }
  if (l31 == 0) {
#pragma unroll
    for (int r = 0; r < 16; ++r)
      red[wave][(r & 3) + 8 * (r >> 2) + 4 * lh] = run[r];
  }
  __syncthreads();
  if (t < 128) {
    const int rt2 = t >> 5, row = t & 31;
    const float v0 = red[rt2 * 2][row], v1 = red[rt2 * 2 + 1][row];
    const size_t o = (size_t)(n * 2 + qhalf) * P + p0 + rt2 * 32 + row;
    if (PASS == 0)
      ws[OFF_RMAXH + o] = fmaxf(v0, v1);
    else
      ws[OFF_SUMH + o] = v0 + v1;
  }
}

// ---------- combine kernels ----------
__global__ void k_alpha(float* __restrict__ ws) {
  const int i = blockIdx.x * 256 + threadIdx.x;  // 0 .. NB*P-1
  const int n = i >> 12, p = i & (P - 1);
  const float rm = fmaxf(ws[OFF_RMAXH + (size_t)(n * 2) * P + p],
                         ws[OFF_RMAXH + (size_t)(n * 2 + 1) * P + p]);
  ws[OFF_RMAX + (size_t)n * P + p]  = rm;
  ws[OFF_ALPHA + (size_t)n * P + p] = 1.0f / (HB * (1.0f - rm + EPSD));
}

__global__ void k_L(float* __restrict__ ws) {
  const int i = blockIdx.x * 256 + threadIdx.x;
  const int n = i >> 12, p = i & (P - 1);
  const float s = ws[OFF_SUMH + (size_t)(n * 2) * P + p] +
                  ws[OFF_SUMH + (size_t)(n * 2 + 1) * P + p];
  const float a_ = ws[OFF_ALPHA + (size_t)n * P + p];
  const float rm = ws[OFF_RMAX + (size_t)n * P + p];
  ws[OFF_LROW + (size_t)n * P + p] = fmaf(a_, rm, logf(s));
}

// ---------- col pass: partial colmax_q over a p-half ----------
// bid = qstrip*8 + n*2 + phalf. Block: 128 q x 2048 p.
__global__ __launch_bounds__(512, 2) void k_col(float* __restrict__ ws) {
  const int t = threadIdx.x;
  const int wave = t >> 6, l = t & 63, l31 = l & 31, lh = l >> 5, l15 = l31 & 15;
  const int rt = wave >> 1, ct = wave & 1;
  const int bid = blockIdx.x;
  const int phalf = bid & 1, n = (bid >> 1) & 3, qstrip = bid >> 3;
  const int q0 = qstrip * 128;
  const int pbase = phalf * 2048;

  const u16* xn = reinterpret_cast<const u16*>(ws + OFF_XNT) + (size_t)n * P * C;
  const u16* yn = reinterpret_cast<const u16*>(ws + OFF_YNT) + (size_t)n * P * C;
  const float* alp = ws + OFF_ALPHA + (size_t)n * P;
  const float* lrw = ws + OFF_LROW + (size_t)n * P;

  __shared__ __align__(16) u16 Bl[2][128 * 256];
  __shared__ float red[8][32];

  const u16* Ap = yn + (size_t)(q0 + rt * 32 + l31) * 256;
  bf16x8 af[16];
#pragma unroll
  for (int ks = 0; ks < 16; ++ks) af[ks] = ldfrag(Ap + (ks * 2 + lh) * 8);

  float run[16];
#pragma unroll
  for (int r = 0; r < 16; ++r) run[r] = -3.0e38f;

  stage_tile(xn, pbase, Bl[0], t);
  __syncthreads();

  const int r0 = ct * 64 + l31;

  for (int step = 0; step < 16; ++step) {
    const int cur = step & 1;
    if (step + 1 < 16) stage_tile(xn, pbase + (step + 1) * 128, Bl[cur ^ 1], t);
    const u16* Brow = &Bl[cur][(size_t)r0 * 256];

    const int pc0 = pbase + step * 128 + ct * 64 + l31;  // sub0 p; sub1 = +32
    const float a0 = alp[pc0],      L0 = lrw[pc0];
    const float a1 = alp[pc0 + 32], L1 = lrw[pc0 + 32];

    f32x16 a00 = zero16(), a01 = zero16(), a10 = zero16(), a11 = zero16();
#pragma unroll
    for (int ks = 0; ks < 16; ks += 2) {
      const int g0 = ((ks * 2 + lh) ^ l15) * 8;
      const int g1 = ((ks * 2 + 2 + lh) ^ l15) * 8;
      a00 = __builtin_amdgcn_mfma_f32_32x32x16_bf16(af[ks], ldfrag(Brow + g0), a00, 0, 0, 0);
      a10 = __builtin_amdgcn_mfma_f32_32x32x16_bf16(af[ks], ldfrag(Brow + 32 * 256 + g0), a10, 0, 0, 0);
      a01 = __builtin_amdgcn_mfma_f32_32x32x16_bf16(af[ks + 1], ldfrag(Brow + g1), a01, 0, 0, 0);
      a11 = __builtin_amdgcn_mfma_f32_32x32x16_bf16(af[ks + 1], ldfrag(Brow + 32 * 256 + g1), a11, 0, 0, 0);
    }
    const f32x16 s0 = a00 + a01;
    const f32x16 s1 = a10 + a11;
#pragma unroll
    for (int r = 0; r < 16; ++r)
      run[r] = fmaxf(run[r], fmaxf(fmaf(a0, s0[r], -L0), fmaf(a1, s1[r], -L1)));
    __syncthreads();
  }

  // max over the 32 p-lanes; q rows live on (reg, lh)
#pragma unroll
  for (int m = 1; m <= 16; m <<= 1) {
#pragma unroll
    for (int r = 0; r < 16; ++r) run[r] = fmaxf(run[r], __shfl_xor(run[r], m, 64));
  }
  if (l31 == 0) {
#pragma unroll
    for (int r = 0; r < 16; ++r)
      red[wave][(r & 3) + 8 * (r >> 2) + 4 * lh] = run[r];
  }
  __syncthreads();
  if (t < 128) {
    const int rt2 = t >> 5, row = t & 31;
    const float v = fmaxf(red[rt2 * 2][row], red[rt2 * 2 + 1][row]);
    ws[OFF_CMAXH + (size_t)(n * 2 + phalf) * P + q0 + rt2 * 32 + row] = v;
  }
}

// ---------- final scalar ----------
__global__ void k_final(const float* __restrict__ ws, float* __restrict__ out) {
  const int t = threadIdx.x;  // 256
  __shared__ float red[256];
  __shared__ float lsum_s;
  if (t == 0) lsum_s = 0.f;
  for (int n = 0; n < NB; ++n) {
    float e = 0.f;
    for (int q = t; q < P; q += 256) {
      const float m = fmaxf(ws[OFF_CMAXH + (size_t)(n * 2) * P + q],
                            ws[OFF_CMAXH + (size_t)(n * 2 + 1) * P + q]);
      e += __expf(m);
    }
    __syncthreads();
    red[t] = e;
    __syncthreads();
    for (int w = 128; w > 0; w >>= 1) {
      if (t < w) red[t] += red[t + w];
      __syncthreads();
    }
    if (t == 0) lsum_s += -logf(red[0] * (1.0f / P) + EPSL);
  }
  __syncthreads();
  if (t == 0) out[0] = lsum_s * 0.25f;
}

extern "C" void kernel_launch(void* const* d_in, const int* in_sizes, int n_in,
                              void* d_out, int out_size, void* d_ws, size_t ws_size,
                              hipStream_t stream) {
  const float* x  = (const float*)d_in[0];  // y      -> x in contextual_loss
  const float* yh = (const float*)d_in[1];  // y_hat  -> y in contextual_loss
  float* ws  = (float*)d_ws;
  float* out = (float*)d_out;

  k_mu<<<dim3(C), dim3(256), 0, stream>>>(yh, ws);
  k_norm<<<dim3(NB * 64 * 2), dim3(256), 0, stream>>>(x, yh, ws);
  k_row<0><<<dim3(256), dim3(512), 0, stream>>>(ws);
  k_alpha<<<dim3(NB * P / 256), dim3(256), 0, stream>>>(ws);
  k_row<1><<<dim3(256), dim3(512), 0, stream>>>(ws);
  k_L<<<dim3(NB * P / 256), dim3(256), 0, stream>>>(ws);
  k_col<<<dim3(256), dim3(512), 0, stream>>>(ws);
  k_final<<<dim3(1), dim3(256), 0, stream>>>(ws, out);
}